// Round 3
// baseline (959.372 us; speedup 1.0000x reference)
//
#include <hip/hip_runtime.h>
#include <math.h>

// Problem constants
#define BATCH 2
#define SEQ   2048
#define NHEAD 16
#define EMB   1024
#define N3E   3072
#define VQL   2016   // SEQ - RESIDUAL_LEN

typedef unsigned short ushort8_t __attribute__((ext_vector_type(8)));
typedef unsigned short ushort4_t __attribute__((ext_vector_type(4)));

__device__ __forceinline__ float clipf(float x) {
    return fminf(fmaxf(x, -10000.0f), 10000.0f);
}
__device__ __forceinline__ float bf2f(unsigned short u) {
    return __uint_as_float(((unsigned)u) << 16);
}
__device__ __forceinline__ unsigned short f2bf(float f) {  // round-to-nearest-even
    unsigned u = __float_as_uint(f);
    unsigned r = 0x7FFFu + ((u >> 16) & 1u);
    return (unsigned short)((u + r) >> 16);
}

// ---------------------------------------------------------------------------
// QKV GEMM fused with KIVI quantization.
// C[m][n] = sum_k X[m][k]*W[k][n] + b[n]; M=4096, K=1024, N=3072.
// 64x64 tile per block == (64 tokens) x (one head's 64 dims) -> quant groups
// align exactly with the tile. Q written fp32; K,V fake-quantized in fp32
// then stored bf16.
// ---------------------------------------------------------------------------
__global__ __launch_bounds__(256) void gemm_qkv_fused(
    const float* __restrict__ X, const float* __restrict__ W,
    const float* __restrict__ bias,
    float* __restrict__ Q, unsigned short* __restrict__ Kb,
    unsigned short* __restrict__ V)
{
    const int KD = 1024, N = N3E;
    __shared__ float As[16][68];   // As[kk][m]
    __shared__ float Bs[16][68];   // Bs[kk][n]
    __shared__ float redmn[4][64];
    __shared__ float redmx[4][64];

    const int tid  = threadIdx.x;
    const int row0 = blockIdx.y * 64;
    const int col0 = blockIdx.x * 64;
    const int tr = (tid >> 4) << 2;
    const int tc = (tid & 15) << 2;
    const int ar = tid >> 2, ac = (tid & 3) << 2;
    const int br = tid >> 4, bc = (tid & 15) << 2;
    float acc[4][4] = {};

    for (int k0 = 0; k0 < KD; k0 += 16) {
        float4 a4 = *(const float4*)(X + (size_t)(row0 + ar) * KD + k0 + ac);
        As[ac + 0][ar] = a4.x; As[ac + 1][ar] = a4.y;
        As[ac + 2][ar] = a4.z; As[ac + 3][ar] = a4.w;
        *(float4*)&Bs[br][bc] = *(const float4*)(W + (size_t)(k0 + br) * N + col0 + bc);
        __syncthreads();
        #pragma unroll
        for (int kk = 0; kk < 16; ++kk) {
            float a[4], b[4];
            *(float4*)a = *(const float4*)&As[kk][tr];
            *(float4*)b = *(const float4*)&Bs[kk][tc];
            #pragma unroll
            for (int i = 0; i < 4; ++i)
                #pragma unroll
                for (int j = 0; j < 4; ++j)
                    acc[i][j] += a[i] * b[j];
        }
        __syncthreads();
    }

    // ---- epilogue ----
    const int n0 = col0 + tc;
    const int which = n0 >> 10;      // block-uniform: 0=q,1=k,2=v
    const int e = n0 & 1023;
    const int h = e >> 6, d = e & 63;

    #pragma unroll
    for (int j = 0; j < 4; ++j) {
        float bo = bias[n0 + j];
        #pragma unroll
        for (int i = 0; i < 4; ++i) acc[i][j] += bo;
    }

    if (which == 0) {
        #pragma unroll
        for (int i = 0; i < 4; ++i) {
            int m = row0 + tr + i;
            int batch = m >> 11, s = m & 2047;
            *(float4*)(Q + ((((size_t)batch * NHEAD + h) * SEQ + s) << 6) + d) =
                *(float4*)acc[i];
        }
    } else if (which == 1) {
        // KIVI key quant: per-channel (column) min/max over the 64 tokens (rows)
        float cv[4][4], cm[4], cx[4];
        #pragma unroll
        for (int j = 0; j < 4; ++j) { cm[j] = INFINITY; cx[j] = -INFINITY; }
        #pragma unroll
        for (int i = 0; i < 4; ++i)
            #pragma unroll
            for (int j = 0; j < 4; ++j) {
                float v = clipf(acc[i][j]);
                cv[i][j] = v;
                cm[j] = fminf(cm[j], v);
                cx[j] = fmaxf(cx[j], v);
            }
        // reduce across row-groups within wave (lanes +-16, +-32)
        #pragma unroll
        for (int msk = 16; msk < 64; msk <<= 1)
            #pragma unroll
            for (int j = 0; j < 4; ++j) {
                cm[j] = fminf(cm[j], __shfl_xor(cm[j], msk));
                cx[j] = fmaxf(cx[j], __shfl_xor(cx[j], msk));
            }
        // cross-wave via LDS
        int wave = tid >> 6, lane = tid & 63;
        if (lane < 16) {
            #pragma unroll
            for (int j = 0; j < 4; ++j) { redmn[wave][tc + j] = cm[j]; redmx[wave][tc + j] = cx[j]; }
        }
        __syncthreads();
        #pragma unroll
        for (int j = 0; j < 4; ++j) {
            float mn = fminf(fminf(redmn[0][tc + j], redmn[1][tc + j]),
                             fminf(redmn[2][tc + j], redmn[3][tc + j]));
            float mx = fmaxf(fmaxf(redmx[0][tc + j], redmx[1][tc + j]),
                             fmaxf(redmx[2][tc + j], redmx[3][tc + j]));
            float scale = fmaxf((mx - mn) / 3.0f, 1e-8f);
            #pragma unroll
            for (int i = 0; i < 4; ++i)
                cv[i][j] = rintf((cv[i][j] - mn) / scale) * scale + mn;
        }
        #pragma unroll
        for (int i = 0; i < 4; ++i) {
            int m = row0 + tr + i;
            int batch = m >> 11, s = m & 2047;
            ushort4_t o;
            #pragma unroll
            for (int j = 0; j < 4; ++j) o[j] = f2bf(cv[i][j]);
            *(ushort4_t*)(Kb + ((((size_t)batch * NHEAD + h) * SEQ + s) << 6) + d) = o;
        }
    } else {
        // KIVI value quant: per-token (row) min/max over 64 channels; s<2016 only
        float cv[4][4], rm[4], rx[4];
        #pragma unroll
        for (int i = 0; i < 4; ++i) {
            rm[i] = INFINITY; rx[i] = -INFINITY;
            #pragma unroll
            for (int j = 0; j < 4; ++j) {
                float v = clipf(acc[i][j]);
                cv[i][j] = v;
                rm[i] = fminf(rm[i], v);
                rx[i] = fmaxf(rx[i], v);
            }
        }
        #pragma unroll
        for (int msk = 1; msk < 16; msk <<= 1)
            #pragma unroll
            for (int i = 0; i < 4; ++i) {
                rm[i] = fminf(rm[i], __shfl_xor(rm[i], msk));
                rx[i] = fmaxf(rx[i], __shfl_xor(rx[i], msk));
            }
        #pragma unroll
        for (int i = 0; i < 4; ++i) {
            int m = row0 + tr + i;
            int batch = m >> 11, s = m & 2047;
            ushort4_t o;
            if (s < VQL) {
                float scale = fmaxf((rx[i] - rm[i]) / 3.0f, 1e-8f);
                #pragma unroll
                for (int j = 0; j < 4; ++j)
                    o[j] = f2bf(rintf((cv[i][j] - rm[i]) / scale) * scale + rm[i]);
            } else {
                #pragma unroll
                for (int j = 0; j < 4; ++j) o[j] = f2bf(acc[i][j]);  // raw tail, unclipped
            }
            *(ushort4_t*)(V + ((((size_t)batch * NHEAD + h) * SEQ + s) << 6) + d) = o;
        }
    }
}

// ---------------------------------------------------------------------------
// Flash attention (fp32 math), causal, scale 1/8. Q fp32, K/V bf16, all
// [B,H,S,D]. Output y written fp32 OVER the Q buffer (same [B,H,S,D] layout):
// block (qt,bh) is the only reader of Q-tile (qt,bh) and reads it into LDS at
// block start, so overwriting it in the epilogue is race-free.
// ---------------------------------------------------------------------------
__device__ __forceinline__ void load_tile_T_f32(const float* __restrict__ src,
                                                float (*dst)[68], int tid)
{
    int r = tid >> 2;
    int cb = (tid & 3) << 2;
    #pragma unroll
    for (int rep = 0; rep < 4; ++rep) {
        int c = cb + rep * 16;
        float4 t = *(const float4*)(src + r * 64 + c);
        dst[c + 0][r] = t.x; dst[c + 1][r] = t.y;
        dst[c + 2][r] = t.z; dst[c + 3][r] = t.w;
    }
}

__device__ __forceinline__ void load_tile_T_bf16(const unsigned short* __restrict__ src,
                                                 float (*dst)[68], int tid)
{
    int r = tid >> 2;
    int c0 = (tid & 3) << 4;
    ushort8_t t0 = *(const ushort8_t*)(src + r * 64 + c0);
    ushort8_t t1 = *(const ushort8_t*)(src + r * 64 + c0 + 8);
    #pragma unroll
    for (int j = 0; j < 8; ++j) dst[c0 + j][r] = bf2f(t0[j]);
    #pragma unroll
    for (int j = 0; j < 8; ++j) dst[c0 + 8 + j][r] = bf2f(t1[j]);
}

__device__ __forceinline__ void load_tile_bf16(const unsigned short* __restrict__ src,
                                               float (*dst)[68], int tid)
{
    int r = tid >> 2;
    int c0 = (tid & 3) << 4;
    ushort8_t t0 = *(const ushort8_t*)(src + r * 64 + c0);
    ushort8_t t1 = *(const ushort8_t*)(src + r * 64 + c0 + 8);
    #pragma unroll
    for (int j = 0; j < 8; ++j) dst[r][c0 + j] = bf2f(t0[j]);
    #pragma unroll
    for (int j = 0; j < 8; ++j) dst[r][c0 + 8 + j] = bf2f(t1[j]);
}

__global__ __launch_bounds__(256) void attn_kernel(
    float* __restrict__ QY,               // fp32 [B,H,S,D]; y overwrites q
    const unsigned short* __restrict__ K, // bf16 [B,H,S,D]
    const unsigned short* __restrict__ V) // bf16 [B,H,S,D]
{
    __shared__ float QsT[64][68];
    __shared__ float KsT[64][68];
    __shared__ float Vs[64][68];
    __shared__ float PsT[64][68];

    const int tid = threadIdx.x;
    const int qt  = blockIdx.x;
    const int bh  = blockIdx.y;
    const size_t base = (size_t)bh * (SEQ * 64);

    load_tile_T_f32(QY + base + (size_t)qt * 4096, QsT, tid);

    const int tr = (tid >> 4) << 2;
    const int tc = (tid & 15) << 2;
    float acc[4][4] = {};
    float mrow[4] = {-INFINITY, -INFINITY, -INFINITY, -INFINITY};
    float lrow[4] = {};
    const float sc = 0.125f;

    for (int jt = 0; jt <= qt; ++jt) {
        __syncthreads();   // protect KsT/Vs/PsT (+ QsT on first iter)
        load_tile_T_bf16(K + base + (size_t)jt * 4096, KsT, tid);
        load_tile_bf16  (V + base + (size_t)jt * 4096, Vs, tid);
        __syncthreads();

        // S = Q K^T
        float s[4][4] = {};
        #pragma unroll 8
        for (int kk = 0; kk < 64; ++kk) {
            float a[4], bb[4];
            *(float4*)a  = *(const float4*)&QsT[kk][tr];
            *(float4*)bb = *(const float4*)&KsT[kk][tc];
            #pragma unroll
            for (int i = 0; i < 4; ++i)
                #pragma unroll
                for (int j = 0; j < 4; ++j)
                    s[i][j] += a[i] * bb[j];
        }

        const bool diag = (jt == qt);
        float tmax[4];
        #pragma unroll
        for (int i = 0; i < 4; ++i) {
            #pragma unroll
            for (int j = 0; j < 4; ++j) {
                float v = s[i][j] * sc;
                if (diag && (tc + j) > (tr + i)) v = -1e30f;
                s[i][j] = v;
            }
            tmax[i] = fmaxf(fmaxf(s[i][0], s[i][1]), fmaxf(s[i][2], s[i][3]));
        }
        #pragma unroll
        for (int msk = 1; msk < 16; msk <<= 1)
            #pragma unroll
            for (int i = 0; i < 4; ++i)
                tmax[i] = fmaxf(tmax[i], __shfl_xor(tmax[i], msk));

        float psum[4];
        #pragma unroll
        for (int i = 0; i < 4; ++i) {
            float mnew  = fmaxf(mrow[i], tmax[i]);
            float alpha = __expf(mrow[i] - mnew);
            mrow[i] = mnew;
            lrow[i] *= alpha;
            #pragma unroll
            for (int c = 0; c < 4; ++c) acc[i][c] *= alpha;
            float ps = 0.0f;
            #pragma unroll
            for (int j = 0; j < 4; ++j) {
                float p = __expf(s[i][j] - mnew);
                ps += p;
                PsT[tc + j][tr + i] = p;
            }
            psum[i] = ps;
        }
        #pragma unroll
        for (int msk = 1; msk < 16; msk <<= 1)
            #pragma unroll
            for (int i = 0; i < 4; ++i)
                psum[i] += __shfl_xor(psum[i], msk);
        #pragma unroll
        for (int i = 0; i < 4; ++i) lrow[i] += psum[i];

        __syncthreads();   // PsT ready; Vs still valid

        // O += P V
        #pragma unroll 8
        for (int j = 0; j < 64; ++j) {
            float p[4], vv[4];
            *(float4*)p  = *(const float4*)&PsT[j][tr];
            *(float4*)vv = *(const float4*)&Vs[j][tc];
            #pragma unroll
            for (int i = 0; i < 4; ++i)
                #pragma unroll
                for (int c = 0; c < 4; ++c)
                    acc[i][c] += p[i] * vv[c];
        }
    }

    // Epilogue: y over q, same [B,H,S,D] tile this block owns
    #pragma unroll
    for (int i = 0; i < 4; ++i) {
        float inv = 1.0f / lrow[i];
        float o[4];
        #pragma unroll
        for (int c = 0; c < 4; ++c) o[c] = acc[i][c] * inv;
        *(float4*)(QY + base + (size_t)qt * 4096 + (size_t)(tr + i) * 64 + tc) = *(float4*)o;
    }
}

// ---------------------------------------------------------------------------
// Proj GEMM: out[m][n] = sum_k Y[m][k]*W[k][n] + b[n]; M=4096, K=N=1024.
// Y is in [B,H,S,D] layout (k index = h*64+d, m = b*2048+s).
// ---------------------------------------------------------------------------
__global__ __launch_bounds__(256) void gemm_proj_kernel(
    const float* __restrict__ Y, const float* __restrict__ W,
    const float* __restrict__ bias, float* __restrict__ C)
{
    const int KD = 1024, N = 1024;
    __shared__ float As[16][68];
    __shared__ float Bs[16][68];
    const int tid  = threadIdx.x;
    const int row0 = blockIdx.y * 64;
    const int col0 = blockIdx.x * 64;
    const int tr = (tid >> 4) << 2;
    const int tc = (tid & 15) << 2;
    const int ar = tid >> 2, ac = (tid & 3) << 2;
    const int br = tid >> 4, bc = (tid & 15) << 2;
    float acc[4][4] = {};

    const int m_a = row0 + ar;
    const int b_a = m_a >> 11, s_a = m_a & 2047;

    for (int k0 = 0; k0 < KD; k0 += 16) {
        int kabs = k0 + ac;
        int h = kabs >> 6, d = kabs & 63;
        float4 a4 = *(const float4*)(Y + ((((size_t)b_a * NHEAD + h) * SEQ + s_a) << 6) + d);
        As[ac + 0][ar] = a4.x; As[ac + 1][ar] = a4.y;
        As[ac + 2][ar] = a4.z; As[ac + 3][ar] = a4.w;
        *(float4*)&Bs[br][bc] = *(const float4*)(W + (size_t)(k0 + br) * N + col0 + bc);
        __syncthreads();
        #pragma unroll
        for (int kk = 0; kk < 16; ++kk) {
            float a[4], b[4];
            *(float4*)a = *(const float4*)&As[kk][tr];
            *(float4*)b = *(const float4*)&Bs[kk][tc];
            #pragma unroll
            for (int i = 0; i < 4; ++i)
                #pragma unroll
                for (int j = 0; j < 4; ++j)
                    acc[i][j] += a[i] * b[j];
        }
        __syncthreads();
    }

    #pragma unroll
    for (int i = 0; i < 4; ++i) {
        int m = row0 + tr + i;
        float o[4];
        #pragma unroll
        for (int j = 0; j < 4; ++j) o[j] = acc[i][j] + bias[col0 + tc + j];
        *(float4*)(C + (size_t)m * N + col0 + tc) = *(float4*)o;
    }
}

// ---------------------------------------------------------------------------
extern "C" void kernel_launch(void* const* d_in, const int* in_sizes, int n_in,
                              void* d_out, int out_size, void* d_ws, size_t ws_size,
                              hipStream_t stream)
{
    const float* x     = (const float*)d_in[0];
    const float* Wqkv  = (const float*)d_in[1];
    const float* bqkv  = (const float*)d_in[2];
    const float* Wproj = (const float*)d_in[3];
    const float* bproj = (const float*)d_in[4];
    float* out = (float*)d_out;

    // Workspace: 32 MiB total.
    //   [0,16MiB)  : q fp32 [B,H,S,D], later overwritten by y fp32 (same layout)
    //   [16,24MiB) : k bf16 [B,H,S,D]
    //   [24,32MiB) : v bf16 [B,H,S,D]
    float*          q  = (float*)d_ws;
    unsigned short* kb = (unsigned short*)((char*)d_ws + (16u << 20));
    unsigned short* vb = (unsigned short*)((char*)d_ws + (24u << 20));

    gemm_qkv_fused<<<dim3(N3E / 64, 4096 / 64), 256, 0, stream>>>(x, Wqkv, bqkv, q, kb, vb);
    attn_kernel<<<dim3(SEQ / 64, BATCH * NHEAD), 256, 0, stream>>>(q, kb, vb);
    gemm_proj_kernel<<<dim3(EMB / 64, 4096 / 64), 256, 0, stream>>>(q, Wproj, bproj, out);
}

// Round 4
// 530.028 us; speedup vs baseline: 1.8100x; 1.8100x over previous
//
#include <hip/hip_runtime.h>
#include <math.h>

// Problem constants
#define BATCH 2
#define SEQ   2048
#define NHEAD 16
#define EMB   1024
#define N3E   3072
#define VQL   2016   // SEQ - RESIDUAL_LEN

typedef unsigned short ushort8_t __attribute__((ext_vector_type(8)));
typedef unsigned short ushort4_t __attribute__((ext_vector_type(4)));
typedef short bf16x8 __attribute__((ext_vector_type(8)));
typedef float f32x4 __attribute__((ext_vector_type(4)));

__device__ __forceinline__ float clipf(float x) {
    return fminf(fmaxf(x, -10000.0f), 10000.0f);
}
__device__ __forceinline__ float bf2f(unsigned short u) {
    return __uint_as_float(((unsigned)u) << 16);
}
__device__ __forceinline__ unsigned short f2bf(float f) {  // round-to-nearest-even
    unsigned u = __float_as_uint(f);
    unsigned r = 0x7FFFu + ((u >> 16) & 1u);
    return (unsigned short)((u + r) >> 16);
}

// ---------------------------------------------------------------------------
// QKV GEMM fused with KIVI quantization (fp32 math — exact quant boundaries).
// Q -> fp32 [B,H,S,D]; K -> bf16 [B,H,S,D]; V -> bf16 TRANSPOSED [B,H,D,S].
// ---------------------------------------------------------------------------
__global__ __launch_bounds__(256) void gemm_qkv_fused(
    const float* __restrict__ X, const float* __restrict__ W,
    const float* __restrict__ bias,
    float* __restrict__ Q, unsigned short* __restrict__ Kb,
    unsigned short* __restrict__ Vt)
{
    const int KD = 1024, N = N3E;
    __shared__ float As[16][68];
    __shared__ float Bs[16][68];
    __shared__ float redmn[4][64];
    __shared__ float redmx[4][64];

    const int tid  = threadIdx.x;
    const int row0 = blockIdx.y * 64;
    const int col0 = blockIdx.x * 64;
    const int tr = (tid >> 4) << 2;
    const int tc = (tid & 15) << 2;
    const int ar = tid >> 2, ac = (tid & 3) << 2;
    const int br = tid >> 4, bc = (tid & 15) << 2;
    float acc[4][4] = {};

    for (int k0 = 0; k0 < KD; k0 += 16) {
        float4 a4 = *(const float4*)(X + (size_t)(row0 + ar) * KD + k0 + ac);
        As[ac + 0][ar] = a4.x; As[ac + 1][ar] = a4.y;
        As[ac + 2][ar] = a4.z; As[ac + 3][ar] = a4.w;
        *(float4*)&Bs[br][bc] = *(const float4*)(W + (size_t)(k0 + br) * N + col0 + bc);
        __syncthreads();
        #pragma unroll
        for (int kk = 0; kk < 16; ++kk) {
            float a[4], b[4];
            *(float4*)a = *(const float4*)&As[kk][tr];
            *(float4*)b = *(const float4*)&Bs[kk][tc];
            #pragma unroll
            for (int i = 0; i < 4; ++i)
                #pragma unroll
                for (int j = 0; j < 4; ++j)
                    acc[i][j] += a[i] * b[j];
        }
        __syncthreads();
    }

    // ---- epilogue ----
    const int n0 = col0 + tc;
    const int which = n0 >> 10;      // block-uniform: 0=q,1=k,2=v
    const int e = n0 & 1023;
    const int h = e >> 6, d = e & 63;

    #pragma unroll
    for (int j = 0; j < 4; ++j) {
        float bo = bias[n0 + j];
        #pragma unroll
        for (int i = 0; i < 4; ++i) acc[i][j] += bo;
    }

    if (which == 0) {
        #pragma unroll
        for (int i = 0; i < 4; ++i) {
            int m = row0 + tr + i;
            int batch = m >> 11, s = m & 2047;
            *(float4*)(Q + ((((size_t)batch * NHEAD + h) * SEQ + s) << 6) + d) =
                *(float4*)acc[i];
        }
    } else if (which == 1) {
        // key quant: per-channel min/max over the 64 tokens in this tile
        float cv[4][4], cm[4], cx[4];
        #pragma unroll
        for (int j = 0; j < 4; ++j) { cm[j] = INFINITY; cx[j] = -INFINITY; }
        #pragma unroll
        for (int i = 0; i < 4; ++i)
            #pragma unroll
            for (int j = 0; j < 4; ++j) {
                float v = clipf(acc[i][j]);
                cv[i][j] = v;
                cm[j] = fminf(cm[j], v);
                cx[j] = fmaxf(cx[j], v);
            }
        #pragma unroll
        for (int msk = 16; msk < 64; msk <<= 1)
            #pragma unroll
            for (int j = 0; j < 4; ++j) {
                cm[j] = fminf(cm[j], __shfl_xor(cm[j], msk));
                cx[j] = fmaxf(cx[j], __shfl_xor(cx[j], msk));
            }
        int wave = tid >> 6, lane = tid & 63;
        if (lane < 16) {
            #pragma unroll
            for (int j = 0; j < 4; ++j) { redmn[wave][tc + j] = cm[j]; redmx[wave][tc + j] = cx[j]; }
        }
        __syncthreads();
        #pragma unroll
        for (int j = 0; j < 4; ++j) {
            float mn = fminf(fminf(redmn[0][tc + j], redmn[1][tc + j]),
                             fminf(redmn[2][tc + j], redmn[3][tc + j]));
            float mx = fmaxf(fmaxf(redmx[0][tc + j], redmx[1][tc + j]),
                             fmaxf(redmx[2][tc + j], redmx[3][tc + j]));
            float scale = fmaxf((mx - mn) / 3.0f, 1e-8f);
            #pragma unroll
            for (int i = 0; i < 4; ++i)
                cv[i][j] = rintf((cv[i][j] - mn) / scale) * scale + mn;
        }
        #pragma unroll
        for (int i = 0; i < 4; ++i) {
            int m = row0 + tr + i;
            int batch = m >> 11, s = m & 2047;
            ushort4_t o;
            #pragma unroll
            for (int j = 0; j < 4; ++j) o[j] = f2bf(cv[i][j]);
            *(ushort4_t*)(Kb + ((((size_t)batch * NHEAD + h) * SEQ + s) << 6) + d) = o;
        }
    } else {
        // value quant: per-token min/max over 64 channels; s<2016 only.
        float outv[4][4], rm[4], rx[4];
        #pragma unroll
        for (int i = 0; i < 4; ++i) {
            rm[i] = INFINITY; rx[i] = -INFINITY;
            #pragma unroll
            for (int j = 0; j < 4; ++j) {
                float v = clipf(acc[i][j]);
                outv[i][j] = v;
                rm[i] = fminf(rm[i], v);
                rx[i] = fmaxf(rx[i], v);
            }
        }
        #pragma unroll
        for (int msk = 1; msk < 16; msk <<= 1)
            #pragma unroll
            for (int i = 0; i < 4; ++i) {
                rm[i] = fminf(rm[i], __shfl_xor(rm[i], msk));
                rx[i] = fmaxf(rx[i], __shfl_xor(rx[i], msk));
            }
        const int m0 = row0 + tr;
        const int batch = m0 >> 11, s0 = m0 & 2047;
        #pragma unroll
        for (int i = 0; i < 4; ++i) {
            if (s0 + i < VQL) {
                float scale = fmaxf((rx[i] - rm[i]) / 3.0f, 1e-8f);
                #pragma unroll
                for (int j = 0; j < 4; ++j)
                    outv[i][j] = rintf((outv[i][j] - rm[i]) / scale) * scale + rm[i];
            } else {
                #pragma unroll
                for (int j = 0; j < 4; ++j) outv[i][j] = acc[i][j];  // raw tail
            }
        }
        // transposed store: Vt[b,h,d+j, s0..s0+3]
        #pragma unroll
        for (int j = 0; j < 4; ++j) {
            ushort4_t o;
            #pragma unroll
            for (int i = 0; i < 4; ++i) o[i] = f2bf(outv[i][j]);
            *(ushort4_t*)(Vt + (((size_t)batch * NHEAD + h) * 64 + d + j) * SEQ + s0) = o;
        }
    }
}

// ---------------------------------------------------------------------------
// MFMA flash attention (bf16 inputs, fp32 accum), causal, scale 1/8.
// Q fp32 [B,H,S,D] (y overwrites it), K bf16 [B,H,S,D], V bf16 [B,H,D,S].
// Block = 256 threads = 4 waves; Q-tile 64 rows (16/wave); KV-tile 64.
// mfma_f32_16x16x32_bf16; A: row=l&15,k=(l>>4)*8+j; B: k=(l>>4)*8+j,col=l&15;
// C/D: col=l&15, row=(l>>4)*4+reg  [learn_hip m89/m91].
// ---------------------------------------------------------------------------
__global__ __launch_bounds__(256) void attn_mfma(
    float* __restrict__ QY,
    const unsigned short* __restrict__ K,
    const unsigned short* __restrict__ Vt)
{
    __shared__ unsigned short Ks [64][72];   // [kv][d], pad 72
    __shared__ unsigned short VsT[64][72];   // [d][kv], pad 72
    __shared__ unsigned short Ps [4][16][72];// per-wave P^(A-layout) scratch

    const int tid  = threadIdx.x;
    const int wave = tid >> 6;
    const int lane = tid & 63;
    const int lr   = lane & 15;   // "col" lane index
    const int g    = lane >> 4;   // lane group

    const int bid = blockIdx.x;
    const int qt  = 31 - (bid >> 5);   // longest blocks first
    const int bh  = bid & 31;
    const size_t base = (size_t)bh * (SEQ * 64);

    // Q fragments (registers): q-row = qt*64 + wave*16 + lr
    const int   qrow = qt * 64 + wave * 16 + lr;
    const float* qp  = QY + base + (size_t)qrow * 64;
    bf16x8 aq[2];
    #pragma unroll
    for (int ka = 0; ka < 2; ++ka) {
        float4 f0 = *(const float4*)(qp + ka * 32 + g * 8);
        float4 f1 = *(const float4*)(qp + ka * 32 + g * 8 + 4);
        bf16x8 a;
        a[0] = (short)f2bf(f0.x); a[1] = (short)f2bf(f0.y);
        a[2] = (short)f2bf(f0.z); a[3] = (short)f2bf(f0.w);
        a[4] = (short)f2bf(f1.x); a[5] = (short)f2bf(f1.y);
        a[6] = (short)f2bf(f1.z); a[7] = (short)f2bf(f1.w);
        aq[ka] = a;
    }

    f32x4 o[4] = {};                         // O[q(reg)][d-frag]
    float m[4]   = {-1e30f, -1e30f, -1e30f, -1e30f};
    float lsum[4] = {};
    const float sc = 0.125f;

    const int str = tid >> 2;            // staging row
    const int stc = (tid & 3) << 4;      // staging col (16 ushorts)

    for (int jt = 0; jt <= qt; ++jt) {
        __syncthreads();  // previous tile fully consumed
        {
            const unsigned short* kg = K  + base + ((size_t)(jt * 64 + str) << 6) + stc;
            *(ushort8_t*)&Ks[str][stc]     = *(const ushort8_t*)kg;
            *(ushort8_t*)&Ks[str][stc + 8] = *(const ushort8_t*)(kg + 8);
            const unsigned short* vg = Vt + base + ((size_t)str << 11) + jt * 64 + stc;
            *(ushort8_t*)&VsT[str][stc]     = *(const ushort8_t*)vg;
            *(ushort8_t*)&VsT[str][stc + 8] = *(const ushort8_t*)(vg + 8);
        }
        __syncthreads();

        // ---- S = Q K^T (16 q-rows x 64 kv per wave) ----
        f32x4 s[4] = {};
        #pragma unroll
        for (int f = 0; f < 4; ++f) {
            #pragma unroll
            for (int ka = 0; ka < 2; ++ka) {
                bf16x8 bk = *(const bf16x8*)&Ks[f * 16 + lr][ka * 32 + g * 8];
                s[f] = __builtin_amdgcn_mfma_f32_16x16x32_bf16(aq[ka], bk, s[f], 0, 0, 0);
            }
        }

        // ---- online softmax ----
        const bool diag = (jt == qt);
        float mx[4];
        #pragma unroll
        for (int r = 0; r < 4; ++r) {
            const int ql = wave * 16 + g * 4 + r;   // q local in block
            float vmax = -1e30f;
            #pragma unroll
            for (int f = 0; f < 4; ++f) {
                float v = s[f][r] * sc;
                if (diag && (f * 16 + lr) > ql) v = -1e30f;
                s[f][r] = v;
                vmax = fmaxf(vmax, v);
            }
            mx[r] = vmax;
        }
        #pragma unroll
        for (int msk = 1; msk < 16; msk <<= 1)
            #pragma unroll
            for (int r = 0; r < 4; ++r)
                mx[r] = fmaxf(mx[r], __shfl_xor(mx[r], msk));

        float alpha[4], tsum[4];
        #pragma unroll
        for (int r = 0; r < 4; ++r) {
            float mn = fmaxf(m[r], mx[r]);
            alpha[r] = __expf(m[r] - mn);
            m[r] = mn;
            float ts = 0.0f;
            #pragma unroll
            for (int f = 0; f < 4; ++f) {
                float p = __expf(s[f][r] - mn);
                unsigned short ub = f2bf(p);
                Ps[wave][g * 4 + r][f * 16 + lr] = ub;
                ts += bf2f(ub);   // sum exactly what PV will consume
            }
            tsum[r] = ts;
        }
        #pragma unroll
        for (int msk = 1; msk < 16; msk <<= 1)
            #pragma unroll
            for (int r = 0; r < 4; ++r)
                tsum[r] += __shfl_xor(tsum[r], msk);
        #pragma unroll
        for (int r = 0; r < 4; ++r) {
            lsum[r] = lsum[r] * alpha[r] + tsum[r];
            #pragma unroll
            for (int df = 0; df < 4; ++df) o[df][r] *= alpha[r];
        }

        // wave-private P: drain ds_writes before A-frag reads (rule 18)
        asm volatile("s_waitcnt lgkmcnt(0)" ::: "memory");
        __builtin_amdgcn_sched_barrier(0);

        // ---- O += P V ----
        bf16x8 pa[2];
        #pragma unroll
        for (int kb = 0; kb < 2; ++kb)
            pa[kb] = *(const bf16x8*)&Ps[wave][lr][kb * 32 + g * 8];
        #pragma unroll
        for (int df = 0; df < 4; ++df) {
            #pragma unroll
            for (int kb = 0; kb < 2; ++kb) {
                bf16x8 vb = *(const bf16x8*)&VsT[df * 16 + lr][kb * 32 + g * 8];
                o[df] = __builtin_amdgcn_mfma_f32_16x16x32_bf16(pa[kb], vb, o[df], 0, 0, 0);
            }
        }
    }

    // ---- epilogue: y over q (same tile this block owns) ----
    float invl[4];
    #pragma unroll
    for (int r = 0; r < 4; ++r) invl[r] = 1.0f / lsum[r];
    #pragma unroll
    for (int df = 0; df < 4; ++df)
        #pragma unroll
        for (int r = 0; r < 4; ++r) {
            int q = qt * 64 + wave * 16 + g * 4 + r;
            QY[base + (size_t)q * 64 + df * 16 + lr] = o[df][r] * invl[r];
        }
}

// ---------------------------------------------------------------------------
// Proj GEMM: out[m][n] = sum_k Y[m][k]*W[k][n] + b[n]; M=4096, K=N=1024.
// Y in [B,H,S,D] layout (k = h*64+d, m = b*2048+s).
// ---------------------------------------------------------------------------
__global__ __launch_bounds__(256) void gemm_proj_kernel(
    const float* __restrict__ Y, const float* __restrict__ W,
    const float* __restrict__ bias, float* __restrict__ C)
{
    const int KD = 1024, N = 1024;
    __shared__ float As[16][68];
    __shared__ float Bs[16][68];
    const int tid  = threadIdx.x;
    const int row0 = blockIdx.y * 64;
    const int col0 = blockIdx.x * 64;
    const int tr = (tid >> 4) << 2;
    const int tc = (tid & 15) << 2;
    const int ar = tid >> 2, ac = (tid & 3) << 2;
    const int br = tid >> 4, bc = (tid & 15) << 2;
    float acc[4][4] = {};

    const int m_a = row0 + ar;
    const int b_a = m_a >> 11, s_a = m_a & 2047;

    for (int k0 = 0; k0 < KD; k0 += 16) {
        int kabs = k0 + ac;
        int h = kabs >> 6, d = kabs & 63;
        float4 a4 = *(const float4*)(Y + ((((size_t)b_a * NHEAD + h) * SEQ + s_a) << 6) + d);
        As[ac + 0][ar] = a4.x; As[ac + 1][ar] = a4.y;
        As[ac + 2][ar] = a4.z; As[ac + 3][ar] = a4.w;
        *(float4*)&Bs[br][bc] = *(const float4*)(W + (size_t)(k0 + br) * N + col0 + bc);
        __syncthreads();
        #pragma unroll
        for (int kk = 0; kk < 16; ++kk) {
            float a[4], b[4];
            *(float4*)a = *(const float4*)&As[kk][tr];
            *(float4*)b = *(const float4*)&Bs[kk][tc];
            #pragma unroll
            for (int i = 0; i < 4; ++i)
                #pragma unroll
                for (int j = 0; j < 4; ++j)
                    acc[i][j] += a[i] * b[j];
        }
        __syncthreads();
    }

    #pragma unroll
    for (int i = 0; i < 4; ++i) {
        int m = row0 + tr + i;
        float o[4];
        #pragma unroll
        for (int j = 0; j < 4; ++j) o[j] = acc[i][j] + bias[col0 + tc + j];
        *(float4*)(C + (size_t)m * N + col0 + tc) = *(float4*)o;
    }
}

// ---------------------------------------------------------------------------
extern "C" void kernel_launch(void* const* d_in, const int* in_sizes, int n_in,
                              void* d_out, int out_size, void* d_ws, size_t ws_size,
                              hipStream_t stream)
{
    const float* x     = (const float*)d_in[0];
    const float* Wqkv  = (const float*)d_in[1];
    const float* bqkv  = (const float*)d_in[2];
    const float* Wproj = (const float*)d_in[3];
    const float* bproj = (const float*)d_in[4];
    float* out = (float*)d_out;

    // Workspace: 32 MiB.
    //   [0,16MiB)  : q fp32 [B,H,S,D], overwritten by y fp32 (same layout)
    //   [16,24MiB) : k bf16 [B,H,S,D]
    //   [24,32MiB) : v bf16 [B,H,D,S]  (transposed)
    float*          q  = (float*)d_ws;
    unsigned short* kb = (unsigned short*)((char*)d_ws + (16u << 20));
    unsigned short* vt = (unsigned short*)((char*)d_ws + (24u << 20));

    gemm_qkv_fused<<<dim3(N3E / 64, 4096 / 64), 256, 0, stream>>>(x, Wqkv, bqkv, q, kb, vt);
    attn_mfma<<<dim3(32 * 32), 256, 0, stream>>>(q, kb, vt);
    gemm_proj_kernel<<<dim3(EMB / 64, 4096 / 64), 256, 0, stream>>>(q, Wproj, bproj, out);
}

// Round 5
// 310.357 us; speedup vs baseline: 3.0912x; 1.7078x over previous
//
#include <hip/hip_runtime.h>
#include <math.h>

// Problem constants
#define BATCH 2
#define SEQ   2048
#define NHEAD 16
#define EMB   1024
#define N3E   3072
#define VQL   2016   // SEQ - RESIDUAL_LEN

typedef unsigned short ushort8_t __attribute__((ext_vector_type(8)));
typedef unsigned short ushort4_t __attribute__((ext_vector_type(4)));
typedef short bf16x8 __attribute__((ext_vector_type(8)));
typedef float f32x4 __attribute__((ext_vector_type(4)));
typedef unsigned int uint2_t __attribute__((ext_vector_type(2)));
typedef unsigned int uint4_t __attribute__((ext_vector_type(4)));

__device__ __forceinline__ float clipf(float x) {
    return fminf(fmaxf(x, -10000.0f), 10000.0f);
}
__device__ __forceinline__ float bf2f(unsigned short u) {
    return __uint_as_float(((unsigned)u) << 16);
}
__device__ __forceinline__ unsigned short f2bf(float f) {  // round-to-nearest-even
    unsigned u = __float_as_uint(f);
    unsigned r = 0x7FFFu + ((u >> 16) & 1u);
    return (unsigned short)((u + r) >> 16);
}
// pack 2 fp32 -> 2 bf16 in one VGPR (lo in [15:0], hi in [31:16])
__device__ __forceinline__ unsigned cvtpk(float lo, float hi) {
    unsigned r;
    asm("v_cvt_pk_bf16_f32 %0, %1, %2" : "=v"(r) : "v"(lo), "v"(hi));
    return r;
}

// ---------------------------------------------------------------------------
// QKV GEMM via 3-term bf16 split MFMA (6 products: 11,12,21,22,13,31).
// Error ~2^-27 relative -> quant-boundary behavior identical to fp32.
// C[m][n] = sum_k X[m][k]*W[k][n] + b[n]; M=4096,K=1024,N=3072.
// Block 128x128, BK=32, 4 waves (2x2 of 64x64). Epilogue: KIVI quant (fp32,
// exact), Q->bf16 [B,H,S,D], K->bf16 [B,H,S,D], V->bf16 transposed [B,H,D,S].
// ---------------------------------------------------------------------------
#define QK_PAD 40   // row stride 80B: 16B-aligned b128, ~2-way bank alias (free)
__global__ __launch_bounds__(256, 2) void gemm_qkv_mfma(
    const float* __restrict__ X, const float* __restrict__ W,
    const float* __restrict__ bias,
    unsigned short* __restrict__ Qb, unsigned short* __restrict__ Kb,
    unsigned short* __restrict__ Vt)
{
    __shared__ unsigned short A3[3][128][QK_PAD];  // [term][row m][k]
    __shared__ unsigned short B3[3][128][QK_PAD];  // [term][col n][k]

    const int tid  = threadIdx.x;
    const int wave = tid >> 6, lane = tid & 63, lr = lane & 15, g = lane >> 4;
    const int wr = wave >> 1, wc = wave & 1;
    const int row0 = blockIdx.y * 128, col0 = blockIdx.x * 128;

    // staging assignments
    const int ra  = tid >> 1,        ca  = (tid & 1) * 16;   // A: 16 elems/thread
    const int cb4 = (tid & 31) * 4,  kb4 = (tid >> 5) * 4;   // B: 4x4 micro-tile

    const float* gA = X + (size_t)(row0 + ra) * 1024 + ca;
    const float* gB = W + (size_t)kb4 * N3E + col0 + cb4;

    float a_reg[16];
    float b_reg[4][4];

    #pragma unroll
    for (int i = 0; i < 4; ++i) *(float4*)&a_reg[i * 4] = *(const float4*)(gA + i * 4);
    #pragma unroll
    for (int i = 0; i < 4; ++i) *(float4*)b_reg[i] = *(const float4*)(gB + (size_t)i * N3E);

    f32x4 acc[4][4] = {};

    for (int t = 0; t < 32; ++t) {
        __syncthreads();   // previous compute done; LDS free
        // ---- split + write A (8 pairs -> 3 terms) ----
        unsigned pw[3][8];
        #pragma unroll
        for (int p = 0; p < 8; ++p) {
            float x0 = a_reg[2 * p], x1 = a_reg[2 * p + 1];
            unsigned h = cvtpk(x0, x1);
            float h0 = __uint_as_float(h << 16), h1 = __uint_as_float(h & 0xFFFF0000u);
            float r0 = x0 - h0, r1 = x1 - h1;
            unsigned m = cvtpk(r0, r1);
            float m0 = __uint_as_float(m << 16), m1 = __uint_as_float(m & 0xFFFF0000u);
            unsigned l = cvtpk(r0 - m0, r1 - m1);
            pw[0][p] = h; pw[1][p] = m; pw[2][p] = l;
        }
        #pragma unroll
        for (int term = 0; term < 3; ++term) {
            *(uint4_t*)&A3[term][ra][ca]     = *(uint4_t*)&pw[term][0];
            *(uint4_t*)&A3[term][ra][ca + 8] = *(uint4_t*)&pw[term][4];
        }
        // ---- split + write B (4x4 micro-transpose; pairs along k) ----
        #pragma unroll
        for (int j = 0; j < 4; ++j) {
            unsigned wh[2], wm[2], wl[2];
            #pragma unroll
            for (int ii = 0; ii < 2; ++ii) {
                float x0 = b_reg[2 * ii][j], x1 = b_reg[2 * ii + 1][j];
                unsigned h = cvtpk(x0, x1);
                float h0 = __uint_as_float(h << 16), h1 = __uint_as_float(h & 0xFFFF0000u);
                float r0 = x0 - h0, r1 = x1 - h1;
                unsigned m = cvtpk(r0, r1);
                float m0 = __uint_as_float(m << 16), m1 = __uint_as_float(m & 0xFFFF0000u);
                unsigned l = cvtpk(r0 - m0, r1 - m1);
                wh[ii] = h; wm[ii] = m; wl[ii] = l;
            }
            *(uint2_t*)&B3[0][cb4 + j][kb4] = *(uint2_t*)wh;
            *(uint2_t*)&B3[1][cb4 + j][kb4] = *(uint2_t*)wm;
            *(uint2_t*)&B3[2][cb4 + j][kb4] = *(uint2_t*)wl;
        }
        __syncthreads();

        // ---- issue next-tile loads (fly under MFMA) ----
        if (t < 31) {
            #pragma unroll
            for (int i = 0; i < 4; ++i)
                *(float4*)&a_reg[i * 4] = *(const float4*)(gA + (t + 1) * 32 + i * 4);
            #pragma unroll
            for (int i = 0; i < 4; ++i)
                *(float4*)b_reg[i] = *(const float4*)(gB + (size_t)((t + 1) * 32 + i) * N3E);
        }

        // ---- compute: 96 MFMA ----
        bf16x8 af[3][4];
        #pragma unroll
        for (int term = 0; term < 3; ++term)
            #pragma unroll
            for (int m = 0; m < 4; ++m)
                af[term][m] = *(const bf16x8*)&A3[term][wr * 64 + m * 16 + lr][g * 8];
        #pragma unroll
        for (int n = 0; n < 4; ++n) {
            bf16x8 bh = *(const bf16x8*)&B3[0][wc * 64 + n * 16 + lr][g * 8];
            bf16x8 bm = *(const bf16x8*)&B3[1][wc * 64 + n * 16 + lr][g * 8];
            bf16x8 bl = *(const bf16x8*)&B3[2][wc * 64 + n * 16 + lr][g * 8];
            #pragma unroll
            for (int m = 0; m < 4; ++m)
                acc[m][n] = __builtin_amdgcn_mfma_f32_16x16x32_bf16(af[0][m], bh, acc[m][n], 0, 0, 0);
            #pragma unroll
            for (int m = 0; m < 4; ++m)
                acc[m][n] = __builtin_amdgcn_mfma_f32_16x16x32_bf16(af[0][m], bm, acc[m][n], 0, 0, 0);
            #pragma unroll
            for (int m = 0; m < 4; ++m)
                acc[m][n] = __builtin_amdgcn_mfma_f32_16x16x32_bf16(af[1][m], bh, acc[m][n], 0, 0, 0);
            #pragma unroll
            for (int m = 0; m < 4; ++m)
                acc[m][n] = __builtin_amdgcn_mfma_f32_16x16x32_bf16(af[1][m], bm, acc[m][n], 0, 0, 0);
            #pragma unroll
            for (int m = 0; m < 4; ++m)
                acc[m][n] = __builtin_amdgcn_mfma_f32_16x16x32_bf16(af[0][m], bl, acc[m][n], 0, 0, 0);
            #pragma unroll
            for (int m = 0; m < 4; ++m)
                acc[m][n] = __builtin_amdgcn_mfma_f32_16x16x32_bf16(af[2][m], bh, acc[m][n], 0, 0, 0);
        }
    }

    // ================= epilogue =================
    // C frag layout: row = wr*64+m*16+g*4+r, col = wc*64+n*16+lr  [m89/m91]
    const int which = col0 >> 10;                       // block-uniform 0=q,1=k,2=v
    const int hcol  = ((col0 + wc * 64) & 1023) >> 6;   // head (wave-uniform)
    const int b     = row0 >> 11;
    const int s_base = (row0 & 2047) + wr * 64;

    float bo[4];
    #pragma unroll
    for (int n = 0; n < 4; ++n) bo[n] = bias[col0 + wc * 64 + n * 16 + lr];
    #pragma unroll
    for (int m = 0; m < 4; ++m)
        #pragma unroll
        for (int n = 0; n < 4; ++n)
            #pragma unroll
            for (int r = 0; r < 4; ++r)
                acc[m][n][r] += bo[n];

    if (which == 0) {
        unsigned short* qdst = Qb + (((size_t)b * NHEAD + hcol) * SEQ) * 64;
        #pragma unroll
        for (int m = 0; m < 4; ++m)
            #pragma unroll
            for (int r = 0; r < 4; ++r) {
                int s = s_base + m * 16 + g * 4 + r;
                #pragma unroll
                for (int n = 0; n < 4; ++n)
                    qdst[(size_t)s * 64 + n * 16 + lr] = f2bf(acc[m][n][r]);
            }
    } else if (which == 1) {
        // key quant: per-channel min/max over this wave's 64 tokens (one group)
        #pragma unroll
        for (int n = 0; n < 4; ++n) {
            float cmn = INFINITY, cmx = -INFINITY;
            #pragma unroll
            for (int m = 0; m < 4; ++m)
                #pragma unroll
                for (int r = 0; r < 4; ++r) {
                    float v = clipf(acc[m][n][r]);
                    acc[m][n][r] = v;
                    cmn = fminf(cmn, v); cmx = fmaxf(cmx, v);
                }
            cmn = fminf(cmn, __shfl_xor(cmn, 16)); cmx = fmaxf(cmx, __shfl_xor(cmx, 16));
            cmn = fminf(cmn, __shfl_xor(cmn, 32)); cmx = fmaxf(cmx, __shfl_xor(cmx, 32));
            float scale = fmaxf((cmx - cmn) / 3.0f, 1e-8f);
            #pragma unroll
            for (int m = 0; m < 4; ++m)
                #pragma unroll
                for (int r = 0; r < 4; ++r)
                    acc[m][n][r] = rintf((acc[m][n][r] - cmn) / scale) * scale + cmn;
        }
        unsigned short* kdst = Kb + (((size_t)b * NHEAD + hcol) * SEQ) * 64;
        #pragma unroll
        for (int m = 0; m < 4; ++m)
            #pragma unroll
            for (int r = 0; r < 4; ++r) {
                int s = s_base + m * 16 + g * 4 + r;
                #pragma unroll
                for (int n = 0; n < 4; ++n)
                    kdst[(size_t)s * 64 + n * 16 + lr] = f2bf(acc[m][n][r]);
            }
    } else {
        // value quant: per-token min/max over 64 channels (this wave's head)
        #pragma unroll
        for (int m = 0; m < 4; ++m)
            #pragma unroll
            for (int r = 0; r < 4; ++r) {
                float c[4];
                #pragma unroll
                for (int n = 0; n < 4; ++n) c[n] = clipf(acc[m][n][r]);
                float mn = fminf(fminf(c[0], c[1]), fminf(c[2], c[3]));
                float mx = fmaxf(fmaxf(c[0], c[1]), fmaxf(c[2], c[3]));
                #pragma unroll
                for (int msk = 1; msk < 16; msk <<= 1) {
                    mn = fminf(mn, __shfl_xor(mn, msk));
                    mx = fmaxf(mx, __shfl_xor(mx, msk));
                }
                int s = s_base + m * 16 + g * 4 + r;
                if (s < VQL) {
                    float scale = fmaxf((mx - mn) / 3.0f, 1e-8f);
                    #pragma unroll
                    for (int n = 0; n < 4; ++n)
                        acc[m][n][r] = rintf((c[n] - mn) / scale) * scale + mn;
                }
                // else: raw unclipped tail (acc already has bias)
            }
        // transposed store Vt[b,h,d,s], ushort4 along s
        #pragma unroll
        for (int m = 0; m < 4; ++m)
            #pragma unroll
            for (int n = 0; n < 4; ++n) {
                ushort4_t o;
                #pragma unroll
                for (int r = 0; r < 4; ++r) o[r] = f2bf(acc[m][n][r]);
                *(ushort4_t*)(Vt + ((((size_t)b * NHEAD + hcol) * 64) + n * 16 + lr) * SEQ
                                 + s_base + m * 16 + g * 4) = o;
            }
    }
}

// ---------------------------------------------------------------------------
// MFMA flash attention (bf16, fp32 accum), causal, scale 1/8.
// Q bf16 [B,H,S,D] (y overwrites it, bf16), K bf16 [B,H,S,D], V bf16 [B,H,D,S].
// ---------------------------------------------------------------------------
__global__ __launch_bounds__(256) void attn_mfma(
    unsigned short* __restrict__ QY,
    const unsigned short* __restrict__ K,
    const unsigned short* __restrict__ Vt)
{
    __shared__ unsigned short Ks [64][72];
    __shared__ unsigned short VsT[64][72];
    __shared__ unsigned short Ps [4][16][72];

    const int tid  = threadIdx.x;
    const int wave = tid >> 6;
    const int lane = tid & 63;
    const int lr   = lane & 15;
    const int g    = lane >> 4;

    const int bid = blockIdx.x;
    const int qt  = 31 - (bid >> 5);
    const int bh  = bid & 31;
    const size_t base = (size_t)bh * (SEQ * 64);

    const int qrow = qt * 64 + wave * 16 + lr;
    const unsigned short* qp = QY + base + (size_t)qrow * 64;
    bf16x8 aq[2];
    #pragma unroll
    for (int ka = 0; ka < 2; ++ka)
        aq[ka] = *(const bf16x8*)(qp + ka * 32 + g * 8);

    f32x4 o[4] = {};
    float m[4]    = {-1e30f, -1e30f, -1e30f, -1e30f};
    float lsum[4] = {};
    const float sc = 0.125f;

    const int str = tid >> 2;
    const int stc = (tid & 3) << 4;

    for (int jt = 0; jt <= qt; ++jt) {
        __syncthreads();
        {
            const unsigned short* kg = K + base + ((size_t)(jt * 64 + str) << 6) + stc;
            *(ushort8_t*)&Ks[str][stc]     = *(const ushort8_t*)kg;
            *(ushort8_t*)&Ks[str][stc + 8] = *(const ushort8_t*)(kg + 8);
            const unsigned short* vg = Vt + base + ((size_t)str << 11) + jt * 64 + stc;
            *(ushort8_t*)&VsT[str][stc]     = *(const ushort8_t*)vg;
            *(ushort8_t*)&VsT[str][stc + 8] = *(const ushort8_t*)(vg + 8);
        }
        __syncthreads();

        f32x4 s[4] = {};
        #pragma unroll
        for (int f = 0; f < 4; ++f) {
            #pragma unroll
            for (int ka = 0; ka < 2; ++ka) {
                bf16x8 bk = *(const bf16x8*)&Ks[f * 16 + lr][ka * 32 + g * 8];
                s[f] = __builtin_amdgcn_mfma_f32_16x16x32_bf16(aq[ka], bk, s[f], 0, 0, 0);
            }
        }

        const bool diag = (jt == qt);
        float mx[4];
        #pragma unroll
        for (int r = 0; r < 4; ++r) {
            const int ql = wave * 16 + g * 4 + r;
            float vmax = -1e30f;
            #pragma unroll
            for (int f = 0; f < 4; ++f) {
                float v = s[f][r] * sc;
                if (diag && (f * 16 + lr) > ql) v = -1e30f;
                s[f][r] = v;
                vmax = fmaxf(vmax, v);
            }
            mx[r] = vmax;
        }
        #pragma unroll
        for (int msk = 1; msk < 16; msk <<= 1)
            #pragma unroll
            for (int r = 0; r < 4; ++r)
                mx[r] = fmaxf(mx[r], __shfl_xor(mx[r], msk));

        float alpha[4], tsum[4];
        #pragma unroll
        for (int r = 0; r < 4; ++r) {
            float mn = fmaxf(m[r], mx[r]);
            alpha[r] = __expf(m[r] - mn);
            m[r] = mn;
            float ts = 0.0f;
            #pragma unroll
            for (int f = 0; f < 4; ++f) {
                float p = __expf(s[f][r] - mn);
                unsigned short ub = f2bf(p);
                Ps[wave][g * 4 + r][f * 16 + lr] = ub;
                ts += bf2f(ub);
            }
            tsum[r] = ts;
        }
        #pragma unroll
        for (int msk = 1; msk < 16; msk <<= 1)
            #pragma unroll
            for (int r = 0; r < 4; ++r)
                tsum[r] += __shfl_xor(tsum[r], msk);
        #pragma unroll
        for (int r = 0; r < 4; ++r) {
            lsum[r] = lsum[r] * alpha[r] + tsum[r];
            #pragma unroll
            for (int df = 0; df < 4; ++df) o[df][r] *= alpha[r];
        }

        asm volatile("s_waitcnt lgkmcnt(0)" ::: "memory");
        __builtin_amdgcn_sched_barrier(0);

        bf16x8 pa[2];
        #pragma unroll
        for (int kb = 0; kb < 2; ++kb)
            pa[kb] = *(const bf16x8*)&Ps[wave][lr][kb * 32 + g * 8];
        #pragma unroll
        for (int df = 0; df < 4; ++df) {
            #pragma unroll
            for (int kb = 0; kb < 2; ++kb) {
                bf16x8 vb = *(const bf16x8*)&VsT[df * 16 + lr][kb * 32 + g * 8];
                o[df] = __builtin_amdgcn_mfma_f32_16x16x32_bf16(pa[kb], vb, o[df], 0, 0, 0);
            }
        }
    }

    float invl[4];
    #pragma unroll
    for (int r = 0; r < 4; ++r) invl[r] = 1.0f / lsum[r];
    #pragma unroll
    for (int df = 0; df < 4; ++df)
        #pragma unroll
        for (int r = 0; r < 4; ++r) {
            int q = qt * 64 + wave * 16 + g * 4 + r;
            QY[base + (size_t)q * 64 + df * 16 + lr] = f2bf(o[df][r] * invl[r]);
        }
}

// ---------------------------------------------------------------------------
// Proj GEMM via bf16 MFMA (smooth path). A = y bf16 [B,H,S,D] (k = h*64+d),
// B = Wproj fp32 -> bf16 staged. Block 128x128, BK=64, double-buffered.
// ---------------------------------------------------------------------------
#define PJ_PAD 72
__global__ __launch_bounds__(256, 2) void gemm_proj_mfma(
    const unsigned short* __restrict__ Y, const float* __restrict__ W,
    const float* __restrict__ bias, float* __restrict__ C)
{
    __shared__ unsigned short A2[2][128][PJ_PAD];  // [row m][k]
    __shared__ unsigned short B2[2][128][PJ_PAD];  // [col n][k]

    const int tid  = threadIdx.x;
    const int wave = tid >> 6, lane = tid & 63, lr = lane & 15, g = lane >> 4;
    const int wr = wave >> 1, wc = wave & 1;
    const int row0 = blockIdx.y * 128, col0 = blockIdx.x * 128;
    const int b = row0 >> 11, s0 = row0 & 2047;

    const int ra  = tid >> 1,       ca  = (tid & 1) * 32;
    const int cb4 = (tid & 31) * 4, kb4 = (tid >> 5) * 4;

    ushort8_t a_reg[4];
    float bw[2][4][4];

    // prologue: load + write buf0 (head h0 = 0)
    {
        const unsigned short* gy = Y + ((((size_t)b * NHEAD + 0) * SEQ + s0 + ra) << 6) + ca;
        #pragma unroll
        for (int i = 0; i < 4; ++i) a_reg[i] = *(const ushort8_t*)(gy + i * 8);
        const float* gw = W + (size_t)kb4 * EMB + col0 + cb4;
        #pragma unroll
        for (int half = 0; half < 2; ++half)
            #pragma unroll
            for (int i = 0; i < 4; ++i)
                *(float4*)bw[half][i] = *(const float4*)(gw + (size_t)(half * 32 + i) * EMB);
        #pragma unroll
        for (int i = 0; i < 4; ++i) *(ushort8_t*)&A2[0][ra][ca + i * 8] = a_reg[i];
        #pragma unroll
        for (int half = 0; half < 2; ++half)
            #pragma unroll
            for (int j = 0; j < 4; ++j) {
                unsigned w2[2];
                w2[0] = cvtpk(bw[half][0][j], bw[half][1][j]);
                w2[1] = cvtpk(bw[half][2][j], bw[half][3][j]);
                *(uint2_t*)&B2[0][cb4 + j][half * 32 + kb4] = *(uint2_t*)w2;
            }
    }
    __syncthreads();

    f32x4 acc[4][4] = {};

    for (int t = 0; t < 16; ++t) {
        const int cur = t & 1;
        // issue next-tile loads
        if (t < 15) {
            const unsigned short* gy =
                Y + ((((size_t)b * NHEAD + (t + 1)) * SEQ + s0 + ra) << 6) + ca;
            #pragma unroll
            for (int i = 0; i < 4; ++i) a_reg[i] = *(const ushort8_t*)(gy + i * 8);
            const float* gw = W + (size_t)((t + 1) * 64 + kb4) * EMB + col0 + cb4;
            #pragma unroll
            for (int half = 0; half < 2; ++half)
                #pragma unroll
                for (int i = 0; i < 4; ++i)
                    *(float4*)bw[half][i] = *(const float4*)(gw + (size_t)(half * 32 + i) * EMB);
        }
        // compute current buffer (loads fly underneath)
        #pragma unroll
        for (int kk = 0; kk < 2; ++kk) {
            bf16x8 af[4];
            #pragma unroll
            for (int m = 0; m < 4; ++m)
                af[m] = *(const bf16x8*)&A2[cur][wr * 64 + m * 16 + lr][kk * 32 + g * 8];
            #pragma unroll
            for (int n = 0; n < 4; ++n) {
                bf16x8 bf = *(const bf16x8*)&B2[cur][wc * 64 + n * 16 + lr][kk * 32 + g * 8];
                #pragma unroll
                for (int m = 0; m < 4; ++m)
                    acc[m][n] = __builtin_amdgcn_mfma_f32_16x16x32_bf16(af[m], bf, acc[m][n], 0, 0, 0);
            }
        }
        // write next buffer
        if (t < 15) {
            const int nxt = cur ^ 1;
            #pragma unroll
            for (int i = 0; i < 4; ++i) *(ushort8_t*)&A2[nxt][ra][ca + i * 8] = a_reg[i];
            #pragma unroll
            for (int half = 0; half < 2; ++half)
                #pragma unroll
                for (int j = 0; j < 4; ++j) {
                    unsigned w2[2];
                    w2[0] = cvtpk(bw[half][0][j], bw[half][1][j]);
                    w2[1] = cvtpk(bw[half][2][j], bw[half][3][j]);
                    *(uint2_t*)&B2[nxt][cb4 + j][half * 32 + kb4] = *(uint2_t*)w2;
                }
        }
        __syncthreads();
    }

    float bo[4];
    #pragma unroll
    for (int n = 0; n < 4; ++n) bo[n] = bias[col0 + wc * 64 + n * 16 + lr];
    #pragma unroll
    for (int m = 0; m < 4; ++m)
        #pragma unroll
        for (int r = 0; r < 4; ++r) {
            int mrow = row0 + wr * 64 + m * 16 + g * 4 + r;
            #pragma unroll
            for (int n = 0; n < 4; ++n)
                C[(size_t)mrow * EMB + col0 + wc * 64 + n * 16 + lr] = acc[m][n][r] + bo[n];
        }
}

// ---------------------------------------------------------------------------
extern "C" void kernel_launch(void* const* d_in, const int* in_sizes, int n_in,
                              void* d_out, int out_size, void* d_ws, size_t ws_size,
                              hipStream_t stream)
{
    const float* x     = (const float*)d_in[0];
    const float* Wqkv  = (const float*)d_in[1];
    const float* bqkv  = (const float*)d_in[2];
    const float* Wproj = (const float*)d_in[3];
    const float* bproj = (const float*)d_in[4];
    float* out = (float*)d_out;

    // Workspace: 24 MiB total.
    //   [0,8MiB)   : q bf16 [B,H,S,D], overwritten by y bf16 (same layout)
    //   [8,16MiB)  : k bf16 [B,H,S,D]
    //   [16,24MiB) : v bf16 [B,H,D,S] (transposed)
    const size_t QKV_ELEMS = (size_t)BATCH * NHEAD * SEQ * 64;  // 4194304
    unsigned short* q  = (unsigned short*)d_ws;
    unsigned short* kb = q + QKV_ELEMS;
    unsigned short* vt = kb + QKV_ELEMS;

    gemm_qkv_mfma<<<dim3(N3E / 128, 4096 / 128), 256, 0, stream>>>(x, Wqkv, bqkv, q, kb, vt);
    attn_mfma<<<dim3(32 * 32), 256, 0, stream>>>(q, kb, vt);
    gemm_proj_mfma<<<dim3(EMB / 128, 4096 / 128), 256, 0, stream>>>(q, Wproj, bproj, out);
}